// Round 4
// baseline (256.474 us; speedup 1.0000x reference)
//
#include <hip/hip_runtime.h>

#define TAGS 256

// DIAGNOSTIC ROUND: run `passes` full sweeps over all rows (passes=2).
// Pass p maps wave w -> row (w + p*rows/2) mod rows — a bijection, so every
// row is computed and stored identically in each pass (output correct), but
// addresses differ across passes so the compiler cannot hoist loads or sink
// stores. Doubling kernel time pushes OUR dispatch above the harness's 81 µs
// fill dispatches, so rocprof's top-5 finally shows our kernel's counters.
//
// Per row: lane i owns tags [4i,4i+4). float4 load -> local max ->
// value-only 6-step shfl_xor butterfly -> ballot+readlane argmax
// (first-occurrence) -> float4 gather of transitions[argmax] -> add -> store.
__global__ __launch_bounds__(256) void crf_head_kernel(
    const float* __restrict__ in,
    const float* __restrict__ trans,
    float* __restrict__ out,
    int rows, int passes)
{
    const int wave = (int)((blockIdx.x * blockDim.x + threadIdx.x) >> 6);
    const int lane = threadIdx.x & 63;
    if (wave >= rows) return;

    const int half = rows >> 1;

    for (int p = 0; p < passes; ++p) {
        int r = wave + p * half;
        if (r >= rows) r -= rows;

        const float4 v = ((const float4*)(in + (size_t)r * TAGS))[lane];

        // lane-local max + first-occurrence local tag index
        const float a  = fmaxf(v.x, v.y);
        const float b  = fmaxf(v.z, v.w);
        const float lm = fmaxf(a, b);
        const int off  = (v.x == lm) ? 0 : (v.y == lm) ? 1
                       : (v.z == lm) ? 2 : 3;
        const int li   = lane * 4 + off;

        // value-only 64-lane max butterfly (6 DS ops)
        float m = lm;
        #pragma unroll
        for (int s = 32; s >= 1; s >>= 1)
            m = fmaxf(m, __shfl_xor(m, s, 64));

        // argmax: lowest lane holding the max owns the lowest tag indices
        const unsigned long long mask = __ballot(lm == m);
        const int src = __ffsll((long long)mask) - 1;        // wave-uniform
        const int mi  = __builtin_amdgcn_readlane(li, src);  // scalar bcast

        // gather transitions[mi] (L2-hot: 256 rows x 1 KB)
        const float4 t = ((const float4*)(trans + (size_t)mi * TAGS))[lane];

        float4 o;
        o.x = v.x + t.x;
        o.y = v.y + t.y;
        o.z = v.z + t.z;
        o.w = v.w + t.w;
        ((float4*)(out + (size_t)r * TAGS))[lane] = o;
    }
}

extern "C" void kernel_launch(void* const* d_in, const int* in_sizes, int n_in,
                              void* d_out, int out_size, void* d_ws, size_t ws_size,
                              hipStream_t stream) {
    const float* in    = (const float*)d_in[0];   // [B, T, TAGS] fp32
    const float* trans = (const float*)d_in[1];   // [TAGS, TAGS] fp32
    float* out = (float*)d_out;                   // [B, T, TAGS] fp32

    const int rows = in_sizes[0] / TAGS;          // B*T = 131072
    const int passes = 2;                         // DIAGNOSTIC: 2 full sweeps

    const int blocks = (rows + 3) / 4;            // one wave per row, 4 waves/block
    crf_head_kernel<<<dim3(blocks), dim3(256), 0, stream>>>(in, trans, out,
                                                            rows, passes);
}